// Round 12
// baseline (287.379 us; speedup 1.0000x reference)
//
#include <hip/hip_runtime.h>
#include <stdint.h>

#define B_ 64
#define N_ 16
#define T_ 128
#define I_ 256
#define H_ 256
#define G_ 768   // 3*H
#define TC 64    // time chunk

typedef __attribute__((ext_vector_type(8))) short bf8;        // 8 bf16 in 4 VGPRs (MFMA frag)
typedef __attribute__((ext_vector_type(8))) unsigned short u16x8;
typedef __attribute__((ext_vector_type(4))) float f4;

static __device__ __forceinline__ unsigned short f2bf(float f) {
    uint32_t u = __builtin_bit_cast(uint32_t, f);
    u += 0x7fffu + ((u >> 16) & 1u);   // RNE
    return (unsigned short)(u >> 16);
}
static __device__ __forceinline__ float bf2f(unsigned short s) {
    return __builtin_bit_cast(float, ((uint32_t)s) << 16);
}
static __device__ __forceinline__ float sigm(float x) {
    return __builtin_amdgcn_rcpf(1.f + __expf(-x));
}

// LDS-only barrier: does not drain vmcnt (global loads/stores stay in flight).
static __device__ __forceinline__ void barrier_lds_only() {
    asm volatile("s_waitcnt lgkmcnt(0)\n\ts_barrier" ::: "memory");
}

// ---- ws layout (bytes) ----
// IH relayout: per (b,n) 96KB block of ushort, slot
//   ((rt*48 + ct)*4 + r)*64 + q*16 + c16,  trow = rt*16 + q*4 + r, g = ct*16 + c16.
#define OFF_WIH   0ull
#define OFF_WHH   6291456ull
#define OFF_BIAS  12582912ull
#define OFF_H32   12632064ull
#define OFF_IH    13680640ull
#define WS_NEEDED (OFF_IH + 100663296ull)

// ---------------- stage 0: convert/shuffle weights ----------------
__global__ __launch_bounds__(256) void prep_kernel(
        const float* __restrict__ wih, const float* __restrict__ whh,
        const float* __restrict__ bih, const float* __restrict__ bhh,
        unsigned char* ws) {
    unsigned short* wih_fr = (unsigned short*)(ws + OFF_WIH);
    unsigned short* whh_fr = (unsigned short*)(ws + OFF_WHH);
    float* bias_f = (float*)(ws + OFF_BIAS);
    int gid = blockIdx.x * blockDim.x + threadIdx.x;
    int nthr = gridDim.x * blockDim.x;

    // fragment order [n][ct(48)][kt(8)][lane(64)][e(8)]
    //   B-frag: col = ct*16 + (lane&15), k = kt*32 + (lane>>4)*8 + e
    for (int o = gid; o < 393216; o += nthr) {
        int lane = o & 63, kt = (o >> 6) & 7, ct = (o >> 9) % 48, n = o / 24576;
        int gcol = ct * 16 + (lane & 15);
        int k0 = kt * 32 + (lane >> 4) * 8;
        const float* s0 = wih + ((size_t)(n * G_ + gcol)) * I_ + k0;
        const float* s1 = whh + ((size_t)(n * G_ + gcol)) * H_ + k0;
        u16x8 v0, v1;
        #pragma unroll
        for (int e = 0; e < 8; e++) { v0[e] = f2bf(s0[e]); v1[e] = f2bf(s1[e]); }
        *(u16x8*)(wih_fr + (size_t)o * 8) = v0;
        *(u16x8*)(whh_fr + (size_t)o * 8) = v1;
    }
    for (int o = gid; o < N_ * G_; o += nthr) {
        int g = o % G_;
        bias_f[o] = bih[o] + (g < 512 ? bhh[o] : 0.f);
    }
}

// ---------------- stage 1: IH = bf16( x @ wih^T + bias_f ), one T-chunk (R10) ----------------
// grid 256 = 1 block/CU; block = (n, bq) covering 4 b-tiles of 64 rows x 768 cols.
// XCD-aware map: n = (blk&7)*2 + (blk>>7).
__global__ __launch_bounds__(1024, 1) void ih_gemm(
        const float* __restrict__ x, const unsigned char* __restrict__ wsr,
        unsigned char* ws, int t0) {
    const unsigned short* wih_fr = (const unsigned short*)(wsr + OFF_WIH);
    const float* bias_f = (const float*)(wsr + OFF_BIAS);
    unsigned short* IH = (unsigned short*)(ws + OFF_IH);

    __shared__ __align__(16) unsigned short As[4 * 64 * 256];   // 128 KB

    int tid = threadIdx.x, lane = tid & 63, w = tid >> 6;
    int blk = blockIdx.x;
    int n = (blk & 7) * 2 + (blk >> 7);
    int bq = (blk >> 3) & 15;
    int c16 = lane & 15, q = lane >> 4, q16 = q * 8;

    // stage A: 4 tiles x 64 rows x 256 k (fp32 -> bf16), swizzled
    #pragma unroll
    for (int i = 0; i < 4; i++) {
        int b = bq * 4 + i;
        const float* xb = x + (((size_t)(b * N_ + n)) * T_ + t0) * I_;
        #pragma unroll
        for (int j = 0; j < 2; j++) {
            int chunk = j * 1024 + tid;
            int row = chunk >> 5, kc = chunk & 31;
            const float* s = xb + row * I_ + kc * 8;
            float4 f0 = *(const float4*)s;
            float4 f1 = *(const float4*)(s + 4);
            u16x8 v;
            v[0] = f2bf(f0.x); v[1] = f2bf(f0.y); v[2] = f2bf(f0.z); v[3] = f2bf(f0.w);
            v[4] = f2bf(f1.x); v[5] = f2bf(f1.y); v[6] = f2bf(f1.z); v[7] = f2bf(f1.w);
            int eoff = i * 16384 + row * 256 + ((kc * 8) ^ ((row & 7) << 3));
            *(u16x8*)(As + eoff) = v;
        }
    }
    __syncthreads();

    // wave w owns col-tiles ct = w*3 .. w*3+2
    const unsigned short* bptr = wih_fr + (((size_t)n * 48 + w * 3) * 8) * 64 * 8;
    f4 zf = {0.f, 0.f, 0.f, 0.f};

    #pragma unroll 1
    for (int i = 0; i < 4; i++) {
        int b = bq * 4 + i;
        const unsigned short* Ai = As + i * 16384;

        f4 acc[4][3];
        #pragma unroll
        for (int rt = 0; rt < 4; rt++)
            #pragma unroll
            for (int c = 0; c < 3; c++) acc[rt][c] = zf;

        bf8 bc[3], bn[3];
        #pragma unroll
        for (int c = 0; c < 3; c++)
            bc[c] = *(const bf8*)(bptr + (((size_t)c * 8 + 0) * 64 + lane) * 8);

        #pragma unroll 1
        for (int kt = 0; kt < 8; kt++) {
            int ktn = (kt + 1) & 7;
            #pragma unroll
            for (int c = 0; c < 3; c++)
                bn[c] = *(const bf8*)(bptr + (((size_t)c * 8 + ktn) * 64 + lane) * 8);
            bf8 a[4];
            #pragma unroll
            for (int rt = 0; rt < 4; rt++) {
                int ar = rt * 16 + c16;
                a[rt] = *(const bf8*)(Ai + ar * 256 + ((kt * 32 + q16) ^ ((ar & 7) << 3)));
            }
            #pragma unroll
            for (int c = 0; c < 3; c++)
                #pragma unroll
                for (int rt = 0; rt < 4; rt++)
                    acc[rt][c] = __builtin_amdgcn_mfma_f32_16x16x32_bf16(a[rt], bc[c], acc[rt][c], 0, 0, 0);
            #pragma unroll
            for (int c = 0; c < 3; c++) bc[c] = bn[c];
        }

        // epilogue: +bias, store bf16 to relayout (128B contiguous per wave-store).
        unsigned short* ob = IH + (size_t)(b * N_ + n) * 49152 + lane;
        #pragma unroll
        for (int c = 0; c < 3; c++) {
            int ct = w * 3 + c;
            float bias = bias_f[n * G_ + ct * 16 + c16];
            #pragma unroll
            for (int rt = 0; rt < 4; rt++) {
                #pragma unroll
                for (int r = 0; r < 4; r++)
                    ob[(((rt * 48 + ct) * 4) + r) * 64] = f2bf(acc[rt][c][r] + bias);
            }
        }
    }
}

// ---------------- stage 2: sequential GRU scan, v3 (16 waves / 4 per SIMD) ----------------
// 256 blocks = (n = blk&15, rg = blk>>4); 1024 thr / 16 waves; wave w owns gate cols
// [w*16, w*16+16) for all 3 gates (ct = g*16 + w). wf[3][8] = 96 VGPR -> fits the
// 128-reg/wave budget at 4 waves/SIMD, doubling TLP at constant MFMA issue count.
// Thread (w, q, c16) owns gate element (brow = rg*4+q, col = w*16+c16).
__global__ __launch_bounds__(1024, 1) void gru_scan(
        const unsigned char* __restrict__ wsr, unsigned char* ws,
        const float* __restrict__ bhh, float* __restrict__ out,
        int chunk, int t0) {
    const unsigned short* IH = (const unsigned short*)(wsr + OFF_IH);
    const unsigned short* whh_fr = (const unsigned short*)(wsr + OFF_WHH);
    float* h32ws = (float*)(ws + OFF_H32);

    __shared__ __align__(16) unsigned short hbf[2][4][272];

    int tid = threadIdx.x, lane = tid & 63, w = tid >> 6;   // w in 0..15
    int n = blockIdx.x & 15, rg = blockIdx.x >> 4;

    int c16 = lane & 15;
    int q = lane >> 4;
    int hrow = c16 >> 2;
    int q16 = q * 8;
    int brow = rg * 4 + q;
    int col = w * 16 + c16;

    // register-resident whh fragments: gate g -> tile ct = g*16 + w
    bf8 wf[3][8];
    #pragma unroll
    for (int g = 0; g < 3; g++) {
        int ct = g * 16 + w;
        #pragma unroll
        for (int kt = 0; kt < 8; kt++)
            wf[g][kt] = *(const bf8*)(whh_fr + ((((size_t)n * 48 + ct) * 8 + kt) * 64 + lane) * 8);
    }

    float bn_hh = bhh[n * G_ + 512 + col];
    float h = 0.f;
    if (chunk) h = h32ws[((size_t)brow * N_ + n) * H_ + col];
    hbf[0][q][col] = f2bf(h);

    // IH read base for this thread: + w*256 (ct offset) + c16; per-step uniform TPART(t).
    const unsigned short* ihb = IH + (size_t)(brow * N_ + n) * 49152 + w * 256 + c16;
    float* op = out + ((size_t)(brow * N_ + n) * T_ + t0) * H_ + col;

    #define TPART(t) (((t) >> 4) * 12288 + ((t) & 3) * 64 + (((t) >> 2) & 3) * 16)

    f4 zf = {0.f, 0.f, 0.f, 0.f};
    __syncthreads();

    #pragma unroll 1
    for (int t = 0; t < TC; t++) {
        // this step's gate inputs (issued early, consumed post-MFMA; IH is L2/L3-hot)
        const unsigned short* p = ihb + TPART(t);
        unsigned short vr = p[0], vz = p[4096], vn = p[8192];

        // hh = h @ whh^T (A rows = replicated h: row i = h[i>>2])
        const unsigned short* hb = &hbf[t & 1][0][0];
        f4 acc0 = zf, acc1 = zf, acc2 = zf;
        #pragma unroll
        for (int kt = 0; kt < 8; kt++) {
            bf8 a = *(const bf8*)(hb + hrow * 272 + kt * 32 + q16);
            acc0 = __builtin_amdgcn_mfma_f32_16x16x32_bf16(a, wf[0][kt], acc0, 0, 0, 0);
            acc1 = __builtin_amdgcn_mfma_f32_16x16x32_bf16(a, wf[1][kt], acc1, 0, 0, 0);
            acc2 = __builtin_amdgcn_mfma_f32_16x16x32_bf16(a, wf[2][kt], acc2, 0, 0, 0);
        }

        // in-register gates: D lane l reg 0 = hh[row q*4][col c16] = h[q]-row result
        float xr = bf2f(vr) + acc0[0];
        float xz = bf2f(vz) + acc1[0];
        float rr = sigm(xr), zz = sigm(xz);
        float pre = bf2f(vn) + rr * (acc2[0] + bn_hh);
        float e2 = __expf(2.f * pre);
        float nv = 1.f - 2.f * __builtin_amdgcn_rcpf(e2 + 1.f);
        float hn = nv + zz * (h - nv);
        h = hn;

        hbf[(t & 1) ^ 1][q][col] = f2bf(hn);
        *op = hn;
        op += H_;

        barrier_lds_only();   // LDS-only wait: global loads/stores stay in flight
    }

    h32ws[((size_t)brow * N_ + n) * H_ + col] = h;
}

extern "C" void kernel_launch(void* const* d_in, const int* in_sizes, int n_in,
                              void* d_out, int out_size, void* d_ws, size_t ws_size,
                              hipStream_t stream) {
    const float* x   = (const float*)d_in[0];
    const float* wih = (const float*)d_in[1];
    const float* whh = (const float*)d_in[2];
    const float* bih = (const float*)d_in[3];
    const float* bhh = (const float*)d_in[4];
    float* out = (float*)d_out;
    unsigned char* ws = (unsigned char*)d_ws;

    if (ws_size < WS_NEEDED) return;

    prep_kernel<<<1024, 256, 0, stream>>>(wih, whh, bih, bhh, ws);
    for (int chunk = 0; chunk < 2; chunk++) {
        int t0 = chunk * TC;
        ih_gemm<<<dim3(256), 1024, 0, stream>>>(x, ws, ws, t0);
        gru_scan<<<dim3(256), 1024, 0, stream>>>(ws, ws, bhh, out, chunk, t0);
    }
}